// Round 13
// baseline (535.983 us; speedup 1.0000x reference)
//
#include <hip/hip_runtime.h>

#define NN 50000      // nodes
#define NN2 50048     // nodes padded to 64
#define NE 800000     // edges
#define NB 128        // graphs / batch
#define SD 64         // state dim / node dim
#define GH 128        // gnn layer1 width
#define GD 64         // gnn layer2 width
#define HID 256       // actor hidden
#define AD 8          // action dim
#define CPAD 53248    // cnt/offs padded: 1024*52
#define NP 8          // hist partitions
#define EB 391        // edge blocks (2048 edges each)
#define MB 782        // 64-row m-tiles (k_pre gemm)
#define NCV 48        // weight-convert blocks (16 per weight)
#define NT 3125       // 16-row tiles (fused kernels), 50000/16 exactly
#define QB 16         // rows per fused tile
#define ECAP 2048     // LDS edge-window capacity (u16); mean 256, huge headroom
#define BST2 130      // wide B-tile stride (shorts), 65 ints
#define TSS 132       // f32 transpose-buffer stride (16B-aligned rows)
#define HSS 136       // Hs row stride (shorts), 272B = 17*16B
#define ASS 72        // As row stride (shorts), 144B = 9*16B

static inline size_t align256(size_t x){ return (x + 255) & ~size_t(255); }

typedef __attribute__((ext_vector_type(8))) short short8v;
typedef __attribute__((ext_vector_type(4))) float f32x4;
typedef __attribute__((ext_vector_type(2))) float f32x2;

__device__ inline unsigned short f2bf(float f){  // RNE
  unsigned u = __builtin_bit_cast(unsigned, f);
  return (unsigned short)((u + 0x7FFFu + ((u >> 16) & 1u)) >> 16);
}
__device__ inline int pk2bf(float a, float b){
  return (int)((unsigned)f2bf(a) | ((unsigned)f2bf(b) << 16));
}
// fp8 e4m3 HW converts
__device__ inline f32x2 fp8x2_to_f32(unsigned short u){
  return __builtin_amdgcn_cvt_pk_f32_fp8((int)u, false);
}
__device__ inline unsigned char f32_to_fp8(float v){
  return (unsigned char)(__builtin_amdgcn_cvt_pk_fp8_f32(v, v, 0, false) & 0xFF);
}
__device__ inline unsigned pack4_fp8(float a, float b, float c, float d){
  int w = __builtin_amdgcn_cvt_pk_fp8_f32(a, b, 0, false);
  w = __builtin_amdgcn_cvt_pk_fp8_f32(c, d, w, true);
  return (unsigned)w;
}
// accumulate 4 fp8 channels of one edge row word
__device__ inline void acc_u32(unsigned u, const float* ax, float* s, float live){
  f32x2 p0 = fp8x2_to_f32((unsigned short)(u & 0xFFFFu));
  f32x2 p1 = fp8x2_to_f32((unsigned short)(u >> 16));
  s[0] = fmaf(live, fmaxf(ax[0] + p0.x, 0.f), s[0]);
  s[1] = fmaf(live, fmaxf(ax[1] + p0.y, 0.f), s[1]);
  s[2] = fmaf(live, fmaxf(ax[2] + p1.x, 0.f), s[2]);
  s[3] = fmaf(live, fmaxf(ax[3] + p1.y, 0.f), s[3]);
}

// ---- dispatch 1: hist [0,EB) ∥ layer-1 GEMM [EB,EB+2*MB) ∥ weight-convert (48) ----
// hist: 8-WAY PARTIAL histograms (partition = blockIdx&7) -> 8x less line contention.
// rank = rank WITHIN partition (atomic return on the partition's counter).
__global__ __launch_bounds__(256)
void k_pre(const int* __restrict__ edst, int* __restrict__ cnt8,
           unsigned short* __restrict__ rank,
           const float* __restrict__ x, const float* __restrict__ w1,
           unsigned char* __restrict__ fA8, unsigned char* __restrict__ fB8,
           const float* __restrict__ w2, const float* __restrict__ w3,
           const float* __restrict__ w4,
           unsigned short* __restrict__ W2t, unsigned short* __restrict__ W3t,
           unsigned short* __restrict__ W4t)
{
  int tid = threadIdx.x;
  if (blockIdx.x < EB){
    int* cp = cnt8 + (size_t)(blockIdx.x & (NP-1))*CPAD;
    int e = blockIdx.x*2048 + tid;
    #pragma unroll
    for (int j = 0; j < 8; ++j){
      int ee = e + j*256;
      if (ee < NE) rank[ee] = (unsigned short)atomicAdd(&cp[edst[ee]], 1);
    }
    return;
  }
  int idx = blockIdx.x - EB;
  if (idx >= 2*MB){                    // weight-convert blocks (coalesced writes)
    int widx = idx - 2*MB;
    int wb = widx >> 4, sub = widx & 15;
    if (wb == 0){                      // W2t[n][k] = w2[k][n], 128x128
      #pragma unroll
      for (int i = 0; i < 4; ++i){
        int o = sub*1024 + tid + i*256;
        int n = o >> 7, k = o & 127;
        W2t[o] = f2bf(w2[k*GH + n]);
      }
    } else if (wb == 1){               // W3t[n][k]; n<64 from w3 rows 0..127, else 128..255
      #pragma unroll
      for (int i = 0; i < 4; ++i){
        int o = sub*1024 + tid + i*256;
        int n = o >> 7, k = o & 127;
        int row = k + ((n >= 64) ? 128 : 0);
        int col = n & 63;
        W3t[o] = f2bf(w3[row*GD + col]);
      }
    } else {                           // W4t[n][k] = w4[k][n], 64x64
      int o = sub*256 + tid;
      int n = o >> 6, k = o & 63;
      W4t[o] = f2bf(w4[k*GD + n]);
    }
    return;
  }
  int m0 = (idx >> 1) * 64;
  int z  = idx & 1;
  const float* W = w1 + (size_t)z*64*GH;
  unsigned char* Out = z ? fB8 : fA8;

  __shared__ float Ts[64*TSS];               // 33.8 KB; aliased by stage bufs
  short* Ah = reinterpret_cast<short*>(Ts);  // [64][40]
  short* Bh = Ah + 64*40;                    // [32][BST2]

  int w = tid >> 6, lane = tid & 63, l15 = tid & 15, quad = lane >> 4;
  f32x4 acc[8];
  #pragma unroll
  for (int t = 0; t < 8; ++t) acc[t] = (f32x4){0.f,0.f,0.f,0.f};

  #pragma unroll
  for (int k0 = 0; k0 < 64; k0 += 32){
    { // A: x fp32 -> bf16, 64 rows x 32 k
      int m = tid >> 2, q = tid & 3;
      float4 v0 = make_float4(0.f,0.f,0.f,0.f), v1 = v0;
      if (m0 + m < NN){
        const float* xr = &x[(size_t)(m0+m)*SD + k0 + q*8];
        v0 = *reinterpret_cast<const float4*>(xr);
        v1 = *reinterpret_cast<const float4*>(xr + 4);
      }
      int4 h;
      h.x = pk2bf(v0.x, v0.y); h.y = pk2bf(v0.z, v0.w);
      h.z = pk2bf(v1.x, v1.y); h.w = pk2bf(v1.z, v1.w);
      *reinterpret_cast<int4*>(&Ah[m*40 + q*8]) = h;
    }
    #pragma unroll
    for (int i = 0; i < 4; ++i){       // B: W fp32 -> bf16 [k][n], 128 cols
      int s = tid + i*256;
      int r = s >> 5, cq = s & 31;
      float4 v = *reinterpret_cast<const float4*>(&W[(size_t)(k0+r)*GH + cq*4]);
      *reinterpret_cast<int*>(&Bh[r*BST2 + cq*4])     = pk2bf(v.x, v.y);
      *reinterpret_cast<int*>(&Bh[r*BST2 + cq*4 + 2]) = pk2bf(v.z, v.w);
    }
    __syncthreads();
    short8v ah = *reinterpret_cast<short8v*>(&Ah[(w*16 + l15)*40 + quad*8]);
    #pragma unroll
    for (int t = 0; t < 8; ++t){
      short8v bh;
      #pragma unroll
      for (int j = 0; j < 8; ++j)
        bh[j] = Bh[(quad*8 + j)*BST2 + t*16 + l15];
      acc[t] = __builtin_amdgcn_mfma_f32_16x16x32_bf16(ah, bh, acc[t], 0, 0, 0);
    }
    __syncthreads();
  }
  #pragma unroll
  for (int r = 0; r < 4; ++r){
    int ml = w*16 + quad*4 + r;
    #pragma unroll
    for (int t = 0; t < 8; ++t)
      Ts[ml*TSS + t*16 + l15] = acc[t][r];
  }
  __syncthreads();
  int row = tid >> 2, seg = tid & 3;
  const float4* tr4 = reinterpret_cast<const float4*>(&Ts[row*TSS + seg*32]);
  float4 f0 = tr4[0], f1 = tr4[1], f2 = tr4[2], f3 = tr4[3];
  uint4 o;
  o.x = pack4_fp8(f0.x,f0.y,f0.z,f0.w);
  o.y = pack4_fp8(f1.x,f1.y,f1.z,f1.w);
  o.z = pack4_fp8(f2.x,f2.y,f2.z,f2.w);
  o.w = pack4_fp8(f3.x,f3.y,f3.z,f3.w);
  *reinterpret_cast<uint4*>(&Out[(size_t)(m0+row)*GH + seg*32]) = o;
  float4 f4 = tr4[4], f5 = tr4[5], f6 = tr4[6], f7 = tr4[7];
  o.x = pack4_fp8(f4.x,f4.y,f4.z,f4.w);
  o.y = pack4_fp8(f5.x,f5.y,f5.z,f5.w);
  o.z = pack4_fp8(f6.x,f6.y,f6.z,f6.w);
  o.w = pack4_fp8(f7.x,f7.y,f7.z,f7.w);
  *reinterpret_cast<uint4*>(&Out[(size_t)(m0+row)*GH + seg*32 + 16]) = o;
}

// scan over 8 partial hists: 1 block x 1024 threads, 52 nodes/thread.
// writes: offs (global node base), offs8[p][v] (partition bases), cnt (totals).
__global__ __launch_bounds__(1024)
void k_scan1(const int* __restrict__ cnt8, int* __restrict__ cnt,
             int* __restrict__ offs, int* __restrict__ offs8){
  __shared__ int sm[1024];
  int t = threadIdx.x;
  int s = 0;
  #pragma unroll
  for (int j = 0; j < 13; ++j){
    #pragma unroll
    for (int p = 0; p < NP; ++p){
      int4 c = reinterpret_cast<const int4*>(cnt8 + (size_t)p*CPAD)[t*13 + j];
      s += c.x + c.y + c.z + c.w;
    }
  }
  sm[t] = s; __syncthreads();
  for (int d = 1; d < 1024; d <<= 1){
    int add = (t >= d) ? sm[t - d] : 0;
    __syncthreads();
    sm[t] += add;
    __syncthreads();
  }
  int run = sm[t] - s;   // exclusive global base
  int base = t*52;
  for (int j = 0; j < 52; ++j){
    int v = base + j;
    offs[v] = run;
    int r2 = run;
    #pragma unroll
    for (int p = 0; p < NP; ++p){
      offs8[(size_t)p*CPAD + v] = r2;
      r2 += cnt8[(size_t)p*CPAD + v];
    }
    cnt[v] = r2 - run;
    run = r2;
  }
}

// place: independent scatter (partition base + within-partition rank)
__global__ void k_place(const int* __restrict__ esrc, const int* __restrict__ edst,
                        const int* __restrict__ offs8,
                        const unsigned short* __restrict__ rank,
                        unsigned short* __restrict__ ssrc){
  const int* op = offs8 + (size_t)(blockIdx.x & (NP-1))*CPAD;
  int e = blockIdx.x*2048 + threadIdx.x;
  #pragma unroll
  for (int j = 0; j < 8; ++j){
    int ee = e + j*256;
    if (ee < NE) ssrc[op[edst[ee]] + (int)rank[ee]] = (unsigned short)esrc[ee];
  }
}

// ---- fused1 (16-row tile, 128 thr): edge-agg L1 -> GEMM(W2t) -> GEMM(W3t) -> fp8 ----
__global__ __launch_bounds__(128)
void k_fused1(const unsigned char* __restrict__ A, const unsigned char* __restrict__ Bm,
              const float* __restrict__ b1, const int* __restrict__ offs,
              const int* __restrict__ cnt, const unsigned short* __restrict__ ssrc,
              const unsigned short* __restrict__ W2t, const unsigned short* __restrict__ W3t,
              const float* __restrict__ b2,
              unsigned char* __restrict__ fC, unsigned char* __restrict__ fD)
{
  __shared__ unsigned short Hs1[QB*HSS];     // gather result tile, bf16 (4352 B)
  __shared__ unsigned short EsHs2[QB*HSS];   // union: Es (phase A) / Hs2 (after GEMM1)
  unsigned short* Es  = EsHs2;               // ECAP=2048 u16 = 4096 B <= 4352 B
  unsigned short* Hs2 = EsHs2;
  int tid = threadIdx.x;
  int m0 = blockIdx.x*QB;

  int beg0 = offs[m0];
  int end0 = offs[m0 + QB];
  int nwin = end0 - beg0;
  for (int i = tid; i < nwin && i < ECAP; i += 128)
    Es[i] = ssrc[beg0 + i];
  __syncthreads();

  // ---- phase A: edge aggregation, 16 nodes x 8 lanes x 16 ch ----
  {
    int vloc = tid >> 3;              // 0..15
    int v = m0 + vloc;                // < NN always (NN % 16 == 0)
    int c = tid & 7;                  // channels 16c .. 16c+15
    float s[16];
    #pragma unroll
    for (int q = 0; q < 16; ++q) s[q] = 0.f;
    int beg = offs[v], n = cnt[v];
    if (n > 0){
      int rel = beg - beg0;
      uint4 au = *reinterpret_cast<const uint4*>(&A[(size_t)v*GH + 16*c]);
      float ax[16];
      #pragma unroll
      for (int wq = 0; wq < 4; ++wq){
        unsigned u = (&au.x)[wq];
        f32x2 p0 = fp8x2_to_f32((unsigned short)(u & 0xFFFFu));
        f32x2 p1 = fp8x2_to_f32((unsigned short)(u >> 16));
        float4 bb = *reinterpret_cast<const float4*>(&b1[16*c + 4*wq]);
        ax[wq*4+0] = p0.x + bb.x; ax[wq*4+1] = p0.y + bb.y;
        ax[wq*4+2] = p1.x + bb.z; ax[wq*4+3] = p1.y + bb.w;
      }
      bool fits = (rel + n) <= ECAP;    // ~always true
      if (fits){
        for (int i = 0; i < n; i += 4){
          int ids[4];
          #pragma unroll
          for (int j = 0; j < 4; ++j){
            int t2 = i + j; t2 = (t2 < n) ? t2 : (n - 1);
            ids[j] = (int)Es[rel + t2];
          }
          uint4 bu[4];
          #pragma unroll
          for (int j = 0; j < 4; ++j)
            bu[j] = *reinterpret_cast<const uint4*>(&Bm[(size_t)ids[j]*GH + 16*c]);
          #pragma unroll
          for (int j = 0; j < 4; ++j){
            float live = (i + j < n) ? 1.f : 0.f;
            #pragma unroll
            for (int wq = 0; wq < 4; ++wq)
              acc_u32((&bu[j].x)[wq], ax + wq*4, s + wq*4, live);
          }
        }
      } else {
        for (int i = 0; i < n; i += 4){
          int ids[4];
          #pragma unroll
          for (int j = 0; j < 4; ++j){
            int t2 = i + j; t2 = (t2 < n) ? t2 : (n - 1);
            ids[j] = (int)ssrc[beg + t2];
          }
          uint4 bu[4];
          #pragma unroll
          for (int j = 0; j < 4; ++j)
            bu[j] = *reinterpret_cast<const uint4*>(&Bm[(size_t)ids[j]*GH + 16*c]);
          #pragma unroll
          for (int j = 0; j < 4; ++j){
            float live = (i + j < n) ? 1.f : 0.f;
            #pragma unroll
            for (int wq = 0; wq < 4; ++wq)
              acc_u32((&bu[j].x)[wq], ax + wq*4, s + wq*4, live);
          }
        }
      }
    }
    uint4 o;
    o.x = (unsigned)pk2bf(s[0], s[1]);   o.y = (unsigned)pk2bf(s[2], s[3]);
    o.z = (unsigned)pk2bf(s[4], s[5]);   o.w = (unsigned)pk2bf(s[6], s[7]);
    *reinterpret_cast<uint4*>(&Hs1[vloc*HSS + 16*c]) = o;
    o.x = (unsigned)pk2bf(s[8], s[9]);   o.y = (unsigned)pk2bf(s[10], s[11]);
    o.z = (unsigned)pk2bf(s[12], s[13]); o.w = (unsigned)pk2bf(s[14], s[15]);
    *reinterpret_cast<uint4*>(&Hs1[vloc*HSS + 16*c + 8]) = o;
  }
  __syncthreads();                      // Es dead after this point

  // ---- GEMM1: Hs1 @ W2t -> h (mean+bias+relu) -> Hs2.  2 waves: 16 rows, cols 64x2
  int w = tid >> 6, lane = tid & 63, l15 = tid & 15, quad = lane >> 4;
  int cb = w * 64;
  f32x4 acc[4];
  #pragma unroll
  for (int t = 0; t < 4; ++t) acc[t] = (f32x4){0.f,0.f,0.f,0.f};
  #pragma unroll
  for (int k0 = 0; k0 < 128; k0 += 32){
    short8v ah = *reinterpret_cast<short8v*>(&Hs1[l15*HSS + k0 + quad*8]);
    #pragma unroll
    for (int t = 0; t < 4; ++t){
      short8v bh = *reinterpret_cast<const short8v*>(&W2t[(cb + t*16 + l15)*GH + k0 + quad*8]);
      acc[t] = __builtin_amdgcn_mfma_f32_16x16x32_bf16(ah, bh, acc[t], 0, 0, 0);
    }
  }
  __syncthreads();                      // all Es reads done before Hs2 writes
  #pragma unroll
  for (int r = 0; r < 4; ++r){
    int ml = quad*4 + r;                // 0..15
    int m = m0 + ml;
    float fcnt = (float)cnt[m];
    float inv = 1.f / fmaxf(fcnt, 1.f);
    #pragma unroll
    for (int t = 0; t < 4; ++t){
      int col = cb + t*16 + l15;
      float v = (acc[t][r] + fcnt * b2[col]) * inv;
      Hs2[ml*HSS + col] = f2bf(fmaxf(v, 0.f));
    }
  }
  __syncthreads();

  // ---- GEMM2: Hs2 @ W3t -> fp8 fC|fD ----
  f32x4 acc2[4];
  #pragma unroll
  for (int t = 0; t < 4; ++t) acc2[t] = (f32x4){0.f,0.f,0.f,0.f};
  #pragma unroll
  for (int k0 = 0; k0 < 128; k0 += 32){
    short8v ah = *reinterpret_cast<short8v*>(&Hs2[l15*HSS + k0 + quad*8]);
    #pragma unroll
    for (int t = 0; t < 4; ++t){
      short8v bh = *reinterpret_cast<const short8v*>(&W3t[(cb + t*16 + l15)*GH + k0 + quad*8]);
      acc2[t] = __builtin_amdgcn_mfma_f32_16x16x32_bf16(ah, bh, acc2[t], 0, 0, 0);
    }
  }
  #pragma unroll
  for (int r = 0; r < 4; ++r){
    int m = m0 + quad*4 + r;
    #pragma unroll
    for (int t = 0; t < 4; ++t){
      int col = cb + t*16 + l15;
      unsigned char o = f32_to_fp8(acc2[t][r]);
      if (col < 64) fC[(size_t)m*GD + col] = o;
      else          fD[(size_t)m*GD + col - 64] = o;
    }
  }
}

// ---- fused2 (16-row tile, 128 thr): edge-agg L2 -> GEMM(W4t)+mean -> graph-sum ----
__global__ __launch_bounds__(128)
void k_fused2(const unsigned char* __restrict__ C, const unsigned char* __restrict__ D,
              const float* __restrict__ b1, const int* __restrict__ offs,
              const int* __restrict__ cnt, const unsigned short* __restrict__ ssrc,
              const unsigned short* __restrict__ W4t, const float* __restrict__ bias,
              const int* __restrict__ nb, float* __restrict__ gsum)
{
  __shared__ unsigned short As[QB*ASS];  // gather result tile, bf16 (2304 B)
  __shared__ float TsEs[QB*65];          // union: Es (phase A) / Ts (epilogue), 4160 B
  unsigned short* Es = reinterpret_cast<unsigned short*>(TsEs);  // 2048 u16 = 4096 B
  float* Ts = TsEs;
  int tid = threadIdx.x;
  int m0 = blockIdx.x*QB;

  int beg0 = offs[m0];
  int end0 = offs[m0 + QB];
  int nwin = end0 - beg0;
  for (int i = tid; i < nwin && i < ECAP; i += 128)
    Es[i] = ssrc[beg0 + i];
  __syncthreads();

  // ---- phase A: edge aggregation, 16 nodes x 8 lanes x 8 ch ----
  {
    int vloc = tid >> 3;
    int v = m0 + vloc;
    int c = tid & 7;                  // channels 8c .. 8c+7
    float s[8];
    #pragma unroll
    for (int q = 0; q < 8; ++q) s[q] = 0.f;
    int beg = offs[v], n = cnt[v];
    if (n > 0){
      int rel = beg - beg0;
      uint2 au = *reinterpret_cast<const uint2*>(&C[(size_t)v*GD + 8*c]);
      float ax[8];
      #pragma unroll
      for (int wq = 0; wq < 2; ++wq){
        unsigned u = (&au.x)[wq];
        f32x2 p0 = fp8x2_to_f32((unsigned short)(u & 0xFFFFu));
        f32x2 p1 = fp8x2_to_f32((unsigned short)(u >> 16));
        float4 bb = *reinterpret_cast<const float4*>(&b1[8*c + 4*wq]);
        ax[wq*4+0] = p0.x + bb.x; ax[wq*4+1] = p0.y + bb.y;
        ax[wq*4+2] = p1.x + bb.z; ax[wq*4+3] = p1.y + bb.w;
      }
      bool fits = (rel + n) <= ECAP;
      if (fits){
        for (int i = 0; i < n; i += 4){
          int ids[4];
          #pragma unroll
          for (int j = 0; j < 4; ++j){
            int t2 = i + j; t2 = (t2 < n) ? t2 : (n - 1);
            ids[j] = (int)Es[rel + t2];
          }
          uint2 du[4];
          #pragma unroll
          for (int j = 0; j < 4; ++j)
            du[j] = *reinterpret_cast<const uint2*>(&D[(size_t)ids[j]*GD + 8*c]);
          #pragma unroll
          for (int j = 0; j < 4; ++j){
            float live = (i + j < n) ? 1.f : 0.f;
            #pragma unroll
            for (int wq = 0; wq < 2; ++wq)
              acc_u32((&du[j].x)[wq], ax + wq*4, s + wq*4, live);
          }
        }
      } else {
        for (int i = 0; i < n; i += 4){
          int ids[4];
          #pragma unroll
          for (int j = 0; j < 4; ++j){
            int t2 = i + j; t2 = (t2 < n) ? t2 : (n - 1);
            ids[j] = (int)ssrc[beg + t2];
          }
          uint2 du[4];
          #pragma unroll
          for (int j = 0; j < 4; ++j)
            du[j] = *reinterpret_cast<const uint2*>(&D[(size_t)ids[j]*GD + 8*c]);
          #pragma unroll
          for (int j = 0; j < 4; ++j){
            float live = (i + j < n) ? 1.f : 0.f;
            #pragma unroll
            for (int wq = 0; wq < 2; ++wq)
              acc_u32((&du[j].x)[wq], ax + wq*4, s + wq*4, live);
          }
        }
      }
    }
    uint4 o;
    o.x = (unsigned)pk2bf(s[0], s[1]); o.y = (unsigned)pk2bf(s[2], s[3]);
    o.z = (unsigned)pk2bf(s[4], s[5]); o.w = (unsigned)pk2bf(s[6], s[7]);
    *reinterpret_cast<uint4*>(&As[vloc*ASS + 8*c]) = o;
  }
  __syncthreads();

  // ---- GEMM: As @ W4t, mean + bias.  2 waves: 16 rows, cols 32x2 ----
  int w = tid >> 6, lane = tid & 63, l15 = tid & 15, quad = lane >> 4;
  int cb = w * 32;
  f32x4 acc[2];
  #pragma unroll
  for (int t = 0; t < 2; ++t) acc[t] = (f32x4){0.f,0.f,0.f,0.f};
  #pragma unroll
  for (int k0 = 0; k0 < 64; k0 += 32){
    short8v ah = *reinterpret_cast<short8v*>(&As[l15*ASS + k0 + quad*8]);
    #pragma unroll
    for (int t = 0; t < 2; ++t){
      short8v bh = *reinterpret_cast<const short8v*>(&W4t[(cb + t*16 + l15)*GD + k0 + quad*8]);
      acc[t] = __builtin_amdgcn_mfma_f32_16x16x32_bf16(ah, bh, acc[t], 0, 0, 0);
    }
  }
  __syncthreads();                      // all Es reads done before Ts writes
  #pragma unroll
  for (int r = 0; r < 4; ++r){
    int ml = quad*4 + r;                // 0..15
    int m = m0 + ml;
    float fcnt = (float)cnt[m];
    float inv = 1.f / fmaxf(fcnt, 1.f);
    #pragma unroll
    for (int t = 0; t < 2; ++t){
      int n = cb + t*16 + l15;
      Ts[ml*65 + n] = (acc[t][r] + fcnt * bias[n]) * inv;
    }
  }
  __syncthreads();
  int col = tid & 63, rg = tid >> 6;    // rg 0..1, 8 rows each
  float a = 0.f; int cur = -1;
  for (int rr = rg*8; rr < rg*8 + 8; ++rr){
    int m = m0 + rr;
    int g = nb[m];
    if (g != cur){ if (cur >= 0) atomicAdd(&gsum[cur*GD + col], a); cur = g; a = 0.f; }
    a += Ts[rr*65 + col];
  }
  if (cur >= 0) atomicAdd(&gsum[cur*GD + col], a);
}

// ---------------- actor head: one block per batch row (divide fused here) -----
__global__ __launch_bounds__(256)
void k_head(const float* __restrict__ state, const float* __restrict__ gsum,
            const int* __restrict__ nb,
            const float* __restrict__ fc1w, const float* __restrict__ fc1b,
            const float* __restrict__ fc2w, const float* __restrict__ fc2b,
            const float* __restrict__ mw, const float* __restrict__ mb,
            const float* __restrict__ lw, const float* __restrict__ lb,
            float* __restrict__ out)
{
  int b = blockIdx.x, t = threadIdx.x;
  __shared__ float z[SD + GD];
  __shared__ float h1[HID];
  __shared__ float h2[HID];
  __shared__ float part[16][17];
  __shared__ int bounds[2];
  if (t < 2){
    int target = b + t;
    int lo = 0, hi = NN;
    while (lo < hi){ int mid = (lo + hi) >> 1; if (nb[mid] < target) lo = mid + 1; else hi = mid; }
    bounds[t] = lo;
  }
  if (t < SD) z[t] = state[b*SD + t];
  __syncthreads();
  if (t >= SD && t < SD + GD){
    float n = (float)(bounds[1] - bounds[0]);
    z[t] = gsum[b*GD + (t - SD)] / fmaxf(n, 1.f);
  }
  __syncthreads();
  float a0 = 0.f, a1 = 0.f;
  #pragma unroll 4
  for (int k = 0; k < SD + GD; k += 2){
    a0 = fmaf(z[k],   fc1w[k*HID + t],     a0);
    a1 = fmaf(z[k+1], fc1w[(k+1)*HID + t], a1);
  }
  h1[t] = fmaxf(a0 + a1 + fc1b[t], 0.f);
  __syncthreads();
  float t0 = 0.f, t1 = 0.f, t2 = 0.f, t3 = 0.f;
  #pragma unroll 4
  for (int k = 0; k < HID; k += 4){
    t0 = fmaf(h1[k],   fc2w[k*HID + t],     t0);
    t1 = fmaf(h1[k+1], fc2w[(k+1)*HID + t], t1);
    t2 = fmaf(h1[k+2], fc2w[(k+2)*HID + t], t2);
    t3 = fmaf(h1[k+3], fc2w[(k+3)*HID + t], t3);
  }
  h2[t] = fmaxf((t0 + t1) + (t2 + t3) + fc2b[t], 0.f);
  __syncthreads();
  { int j = t & 15, p = t >> 4;
    const float* wv = (j < 8) ? mw : lw;
    int colj = j & 7;
    float a = 0.f;
    #pragma unroll
    for (int k = 0; k < 16; ++k)
      a = fmaf(h2[p*16 + k], wv[(p*16 + k)*AD + colj], a);
    part[p][j] = a;
  }
  __syncthreads();
  if (t < 16){
    float sum = (t < 8) ? mb[t] : lb[t - 8];
    #pragma unroll
    for (int p2 = 0; p2 < 16; ++p2) sum += part[p2][t];
    if (t < 8) out[b*AD + t] = sum;
    else       out[NB*AD + b*AD + (t - 8)] = fminf(fmaxf(sum, -20.f), 2.f);
  }
}

extern "C" void kernel_launch(void* const* d_in, const int* in_sizes, int n_in,
                              void* d_out, int out_size, void* d_ws, size_t ws_size,
                              hipStream_t stream)
{
  const float* state = (const float*)d_in[0];
  const float* x     = (const float*)d_in[1];
  const int*   eidx  = (const int*)  d_in[2];
  const int*   nb    = (const int*)  d_in[3];
  const float* g1w1  = (const float*)d_in[4];
  const float* g1b1  = (const float*)d_in[5];
  const float* g1w2  = (const float*)d_in[6];
  const float* g1b2  = (const float*)d_in[7];
  const float* g2w1  = (const float*)d_in[8];
  const float* g2b1  = (const float*)d_in[9];
  const float* g2w2  = (const float*)d_in[10];
  const float* g2b2  = (const float*)d_in[11];
  const float* fc1w  = (const float*)d_in[12];
  const float* fc1b  = (const float*)d_in[13];
  const float* fc2w  = (const float*)d_in[14];
  const float* fc2b  = (const float*)d_in[15];
  const float* mw    = (const float*)d_in[16];
  const float* mb    = (const float*)d_in[17];
  const float* lw    = (const float*)d_in[18];
  const float* lb    = (const float*)d_in[19];

  const int* e_src = eidx;        // edge_index[0]
  const int* e_dst = eidx + NE;   // edge_index[1]

  char* p = (char*)d_ws;
  auto alloc = [&](size_t bytes){ char* r = p; p += align256(bytes); return r; };
  int*   cnt8   = (int*)  alloc((size_t)NP*CPAD*4); // partial hists; contiguous w/ gsum
  float* gsum   = (float*)alloc((size_t)NB*GD*4);
  int*   cnt    = (int*)  alloc((size_t)CPAD*4);    // totals (written by scan)
  int*   offs   = (int*)  alloc((size_t)CPAD*4);
  int*   offs8  = (int*)  alloc((size_t)NP*CPAD*4); // per-partition bases
  unsigned short* rank = (unsigned short*)alloc((size_t)NE*2);
  unsigned short* ssrc = (unsigned short*)alloc((size_t)NE*2);
  unsigned char*  fA8 = (unsigned char*) alloc((size_t)NN2*GH);    // fp8 [NN2,128]
  unsigned char*  fB8 = (unsigned char*) alloc((size_t)NN2*GH);    // fp8 [NN2,128]
  unsigned char*  fC8 = (unsigned char*) alloc((size_t)NN*GD);     // fp8 [NN,64]
  unsigned char*  fD8 = (unsigned char*) alloc((size_t)NN*GD);     // fp8 [NN,64]
  unsigned short* W2t = (unsigned short*)alloc((size_t)GH*GH*2);   // bf16 [128][128] (n,k)
  unsigned short* W3t = (unsigned short*)alloc((size_t)GH*GH*2);   // bf16 [128][128] (n,k)
  unsigned short* W4t = (unsigned short*)alloc((size_t)GD*GD*2);   // bf16 [64][64]  (n,k)

  hipMemsetAsync(cnt8, 0, (size_t)NP*CPAD*4 + (size_t)NB*GD*4, stream);

  dim3 b256(256), b128(128);
  k_pre<<<dim3(EB + MB*2 + NCV), b256, 0, stream>>>(e_dst, cnt8, rank, x, g1w1, fA8, fB8,
                                                    g1w2, g2w1, g2w2, W2t, W3t, W4t);
  k_scan1 <<<dim3(1), dim3(1024), 0, stream>>>(cnt8, cnt, offs, offs8);
  k_place <<<dim3(EB), b256, 0, stream>>>(e_src, e_dst, offs8, rank, ssrc);

  k_fused1<<<dim3(NT), b128, 0, stream>>>(fA8, fB8, g1b1, offs, cnt, ssrc,
                                          W2t, W3t, g1b2, fC8, fD8);
  k_fused2<<<dim3(NT), b128, 0, stream>>>(fC8, fD8, g2b1, offs, cnt, ssrc,
                                          W4t, g2b2, nb, gsum);
  k_head<<<dim3(NB), b256, 0, stream>>>(state, gsum, nb, fc1w, fc1b, fc2w, fc2b,
                                        mw, mb, lw, lb, (float*)d_out);
}

// Round 14
// 420.672 us; speedup vs baseline: 1.2741x; 1.2741x over previous
//
#include <hip/hip_runtime.h>

#define NN 50000      // nodes
#define NN2 50048     // nodes padded to 64
#define NE 800000     // edges
#define NB 128        // graphs / batch
#define SD 64         // state dim / node dim
#define GH 128        // gnn layer1 width
#define GD 64         // gnn layer2 width
#define HID 256       // actor hidden
#define AD 8          // action dim
#define CPAD 53248    // cnt/offs padded: 1024*52
#define NP 8          // hist partitions
#define EB 391        // edge blocks (2048 edges each)
#define MB 782        // 64-row m-tiles (k_pre gemm)
#define NCV 48        // weight-convert blocks (16 per weight)
#define NT 3125       // 16-row tiles (fused kernels), 50000/16 exactly
#define QB 16         // rows per fused tile
#define ECAP 2048     // LDS edge-window capacity (u16); mean 256, huge headroom
#define BST2 130      // wide B-tile stride (shorts), 65 ints
#define TSS 132       // f32 transpose-buffer stride (16B-aligned rows)
#define HSS 136       // Hs row stride (shorts), 272B = 17*16B
#define ASS 72        // As row stride (shorts), 144B = 9*16B

static inline size_t align256(size_t x){ return (x + 255) & ~size_t(255); }

typedef __attribute__((ext_vector_type(8))) short short8v;
typedef __attribute__((ext_vector_type(4))) float f32x4;
typedef __attribute__((ext_vector_type(2))) float f32x2;

__device__ inline unsigned short f2bf(float f){  // RNE
  unsigned u = __builtin_bit_cast(unsigned, f);
  return (unsigned short)((u + 0x7FFFu + ((u >> 16) & 1u)) >> 16);
}
__device__ inline int pk2bf(float a, float b){
  return (int)((unsigned)f2bf(a) | ((unsigned)f2bf(b) << 16));
}
// fp8 e4m3 HW converts
__device__ inline f32x2 fp8x2_to_f32(unsigned short u){
  return __builtin_amdgcn_cvt_pk_f32_fp8((int)u, false);
}
__device__ inline unsigned char f32_to_fp8(float v){
  return (unsigned char)(__builtin_amdgcn_cvt_pk_fp8_f32(v, v, 0, false) & 0xFF);
}
__device__ inline unsigned pack4_fp8(float a, float b, float c, float d){
  int w = __builtin_amdgcn_cvt_pk_fp8_f32(a, b, 0, false);
  w = __builtin_amdgcn_cvt_pk_fp8_f32(c, d, w, true);
  return (unsigned)w;
}
// accumulate 4 fp8 channels of one edge row word
__device__ inline void acc_u32(unsigned u, const float* ax, float* s, float live){
  f32x2 p0 = fp8x2_to_f32((unsigned short)(u & 0xFFFFu));
  f32x2 p1 = fp8x2_to_f32((unsigned short)(u >> 16));
  s[0] = fmaf(live, fmaxf(ax[0] + p0.x, 0.f), s[0]);
  s[1] = fmaf(live, fmaxf(ax[1] + p0.y, 0.f), s[1]);
  s[2] = fmaf(live, fmaxf(ax[2] + p1.x, 0.f), s[2]);
  s[3] = fmaf(live, fmaxf(ax[3] + p1.y, 0.f), s[3]);
}

// ---- dispatch 1: hist [0,EB) ∥ layer-1 GEMM [EB,EB+2*MB) ∥ weight-convert (48) ----
// hist: 8-WAY PARTIAL histograms (partition = blockIdx&7) -> 8x less line contention.
__global__ __launch_bounds__(256)
void k_pre(const int* __restrict__ edst, int* __restrict__ cnt8,
           unsigned short* __restrict__ rank,
           const float* __restrict__ x, const float* __restrict__ w1,
           unsigned char* __restrict__ fA8, unsigned char* __restrict__ fB8,
           const float* __restrict__ w2, const float* __restrict__ w3,
           const float* __restrict__ w4,
           unsigned short* __restrict__ W2t, unsigned short* __restrict__ W3t,
           unsigned short* __restrict__ W4t)
{
  int tid = threadIdx.x;
  if (blockIdx.x < EB){
    int* cp = cnt8 + (size_t)(blockIdx.x & (NP-1))*CPAD;
    int e = blockIdx.x*2048 + tid;
    #pragma unroll
    for (int j = 0; j < 8; ++j){
      int ee = e + j*256;
      if (ee < NE) rank[ee] = (unsigned short)atomicAdd(&cp[edst[ee]], 1);
    }
    return;
  }
  int idx = blockIdx.x - EB;
  if (idx >= 2*MB){                    // weight-convert blocks (coalesced writes)
    int widx = idx - 2*MB;
    int wb = widx >> 4, sub = widx & 15;
    if (wb == 0){                      // W2t[n][k] = w2[k][n], 128x128
      #pragma unroll
      for (int i = 0; i < 4; ++i){
        int o = sub*1024 + tid + i*256;
        int n = o >> 7, k = o & 127;
        W2t[o] = f2bf(w2[k*GH + n]);
      }
    } else if (wb == 1){               // W3t[n][k]; n<64 from w3 rows 0..127, else 128..255
      #pragma unroll
      for (int i = 0; i < 4; ++i){
        int o = sub*1024 + tid + i*256;
        int n = o >> 7, k = o & 127;
        int row = k + ((n >= 64) ? 128 : 0);
        int col = n & 63;
        W3t[o] = f2bf(w3[row*GD + col]);
      }
    } else {                           // W4t[n][k] = w4[k][n], 64x64
      int o = sub*256 + tid;
      int n = o >> 6, k = o & 63;
      W4t[o] = f2bf(w4[k*GD + n]);
    }
    return;
  }
  int m0 = (idx >> 1) * 64;
  int z  = idx & 1;
  const float* W = w1 + (size_t)z*64*GH;
  unsigned char* Out = z ? fB8 : fA8;

  __shared__ float Ts[64*TSS];               // 33.8 KB; aliased by stage bufs
  short* Ah = reinterpret_cast<short*>(Ts);  // [64][40]
  short* Bh = Ah + 64*40;                    // [32][BST2]

  int w = tid >> 6, lane = tid & 63, l15 = tid & 15, quad = lane >> 4;
  f32x4 acc[8];
  #pragma unroll
  for (int t = 0; t < 8; ++t) acc[t] = (f32x4){0.f,0.f,0.f,0.f};

  #pragma unroll
  for (int k0 = 0; k0 < 64; k0 += 32){
    { // A: x fp32 -> bf16, 64 rows x 32 k
      int m = tid >> 2, q = tid & 3;
      float4 v0 = make_float4(0.f,0.f,0.f,0.f), v1 = v0;
      if (m0 + m < NN){
        const float* xr = &x[(size_t)(m0+m)*SD + k0 + q*8];
        v0 = *reinterpret_cast<const float4*>(xr);
        v1 = *reinterpret_cast<const float4*>(xr + 4);
      }
      int4 h;
      h.x = pk2bf(v0.x, v0.y); h.y = pk2bf(v0.z, v0.w);
      h.z = pk2bf(v1.x, v1.y); h.w = pk2bf(v1.z, v1.w);
      *reinterpret_cast<int4*>(&Ah[m*40 + q*8]) = h;
    }
    #pragma unroll
    for (int i = 0; i < 4; ++i){       // B: W fp32 -> bf16 [k][n], 128 cols
      int s = tid + i*256;
      int r = s >> 5, cq = s & 31;
      float4 v = *reinterpret_cast<const float4*>(&W[(size_t)(k0+r)*GH + cq*4]);
      *reinterpret_cast<int*>(&Bh[r*BST2 + cq*4])     = pk2bf(v.x, v.y);
      *reinterpret_cast<int*>(&Bh[r*BST2 + cq*4 + 2]) = pk2bf(v.z, v.w);
    }
    __syncthreads();
    short8v ah = *reinterpret_cast<short8v*>(&Ah[(w*16 + l15)*40 + quad*8]);
    #pragma unroll
    for (int t = 0; t < 8; ++t){
      short8v bh;
      #pragma unroll
      for (int j = 0; j < 8; ++j)
        bh[j] = Bh[(quad*8 + j)*BST2 + t*16 + l15];
      acc[t] = __builtin_amdgcn_mfma_f32_16x16x32_bf16(ah, bh, acc[t], 0, 0, 0);
    }
    __syncthreads();
  }
  #pragma unroll
  for (int r = 0; r < 4; ++r){
    int ml = w*16 + quad*4 + r;
    #pragma unroll
    for (int t = 0; t < 8; ++t)
      Ts[ml*TSS + t*16 + l15] = acc[t][r];
  }
  __syncthreads();
  int row = tid >> 2, seg = tid & 3;
  const float4* tr4 = reinterpret_cast<const float4*>(&Ts[row*TSS + seg*32]);
  float4 f0 = tr4[0], f1 = tr4[1], f2 = tr4[2], f3 = tr4[3];
  uint4 o;
  o.x = pack4_fp8(f0.x,f0.y,f0.z,f0.w);
  o.y = pack4_fp8(f1.x,f1.y,f1.z,f1.w);
  o.z = pack4_fp8(f2.x,f2.y,f2.z,f2.w);
  o.w = pack4_fp8(f3.x,f3.y,f3.z,f3.w);
  *reinterpret_cast<uint4*>(&Out[(size_t)(m0+row)*GH + seg*32]) = o;
  float4 f4 = tr4[4], f5 = tr4[5], f6 = tr4[6], f7 = tr4[7];
  o.x = pack4_fp8(f4.x,f4.y,f4.z,f4.w);
  o.y = pack4_fp8(f5.x,f5.y,f5.z,f5.w);
  o.z = pack4_fp8(f6.x,f6.y,f6.z,f6.w);
  o.w = pack4_fp8(f7.x,f7.y,f7.z,f7.w);
  *reinterpret_cast<uint4*>(&Out[(size_t)(m0+row)*GH + seg*32 + 16]) = o;
}

// scan over 8 partial hists: 1 block x 1024 threads, 52 nodes/thread.
// Pass 2 loads each 4-node chunk's 8 partition-counts as INDEPENDENT int4s
// (register-resident), so no dependent memory chain (R13's 317us bug).
__global__ __launch_bounds__(1024)
void k_scan1(const int* __restrict__ cnt8, int* __restrict__ cnt,
             int* __restrict__ offs, int* __restrict__ offs8){
  __shared__ int sm[1024];
  int t = threadIdx.x;
  int tot = 0;
  #pragma unroll
  for (int j = 0; j < 13; ++j){
    #pragma unroll
    for (int p = 0; p < NP; ++p){
      int4 c = reinterpret_cast<const int4*>(cnt8 + (size_t)p*CPAD)[t*13 + j];
      tot += c.x + c.y + c.z + c.w;
    }
  }
  sm[t] = tot; __syncthreads();
  for (int d = 1; d < 1024; d <<= 1){
    int add = (t >= d) ? sm[t - d] : 0;
    __syncthreads();
    sm[t] += add;
    __syncthreads();
  }
  int run = sm[t] - tot;   // exclusive global base
  for (int j = 0; j < 13; ++j){
    int cv[NP][4];
    #pragma unroll
    for (int p = 0; p < NP; ++p){
      int4 c = reinterpret_cast<const int4*>(cnt8 + (size_t)p*CPAD)[t*13 + j];
      cv[p][0] = c.x; cv[p][1] = c.y; cv[p][2] = c.z; cv[p][3] = c.w;
    }
    int vbase = t*52 + j*4;
    #pragma unroll
    for (int q = 0; q < 4; ++q){
      int v = vbase + q;
      offs[v] = run;
      int r2 = run;
      #pragma unroll
      for (int p = 0; p < NP; ++p){
        offs8[(size_t)p*CPAD + v] = r2;
        r2 += cv[p][q];
      }
      cnt[v] = r2 - run;
      run = r2;
    }
  }
}

// place: independent scatter (partition base + within-partition rank)
__global__ void k_place(const int* __restrict__ esrc, const int* __restrict__ edst,
                        const int* __restrict__ offs8,
                        const unsigned short* __restrict__ rank,
                        unsigned short* __restrict__ ssrc){
  const int* op = offs8 + (size_t)(blockIdx.x & (NP-1))*CPAD;
  int e = blockIdx.x*2048 + threadIdx.x;
  #pragma unroll
  for (int j = 0; j < 8; ++j){
    int ee = e + j*256;
    if (ee < NE) ssrc[op[edst[ee]] + (int)rank[ee]] = (unsigned short)esrc[ee];
  }
}

// ---- fused1 (16-row tile, 128 thr): edge-agg L1 -> GEMM(W2t) -> GEMM(W3t) -> fp8 ----
__global__ __launch_bounds__(128)
void k_fused1(const unsigned char* __restrict__ A, const unsigned char* __restrict__ Bm,
              const float* __restrict__ b1, const int* __restrict__ offs,
              const int* __restrict__ cnt, const unsigned short* __restrict__ ssrc,
              const unsigned short* __restrict__ W2t, const unsigned short* __restrict__ W3t,
              const float* __restrict__ b2,
              unsigned char* __restrict__ fC, unsigned char* __restrict__ fD)
{
  __shared__ unsigned short Hs1[QB*HSS];     // gather result tile, bf16 (4352 B)
  __shared__ unsigned short EsHs2[QB*HSS];   // union: Es (phase A) / Hs2 (after GEMM1)
  unsigned short* Es  = EsHs2;               // ECAP=2048 u16 = 4096 B <= 4352 B
  unsigned short* Hs2 = EsHs2;
  int tid = threadIdx.x;
  int m0 = blockIdx.x*QB;

  int beg0 = offs[m0];
  int end0 = offs[m0 + QB];
  int nwin = end0 - beg0;
  for (int i = tid; i < nwin && i < ECAP; i += 128)
    Es[i] = ssrc[beg0 + i];
  __syncthreads();

  // ---- phase A: edge aggregation, 16 nodes x 8 lanes x 16 ch ----
  {
    int vloc = tid >> 3;              // 0..15
    int v = m0 + vloc;                // < NN always (NN % 16 == 0)
    int c = tid & 7;                  // channels 16c .. 16c+15
    float s[16];
    #pragma unroll
    for (int q = 0; q < 16; ++q) s[q] = 0.f;
    int beg = offs[v], n = cnt[v];
    if (n > 0){
      int rel = beg - beg0;
      uint4 au = *reinterpret_cast<const uint4*>(&A[(size_t)v*GH + 16*c]);
      float ax[16];
      #pragma unroll
      for (int wq = 0; wq < 4; ++wq){
        unsigned u = (&au.x)[wq];
        f32x2 p0 = fp8x2_to_f32((unsigned short)(u & 0xFFFFu));
        f32x2 p1 = fp8x2_to_f32((unsigned short)(u >> 16));
        float4 bb = *reinterpret_cast<const float4*>(&b1[16*c + 4*wq]);
        ax[wq*4+0] = p0.x + bb.x; ax[wq*4+1] = p0.y + bb.y;
        ax[wq*4+2] = p1.x + bb.z; ax[wq*4+3] = p1.y + bb.w;
      }
      bool fits = (rel + n) <= ECAP;    // ~always true
      if (fits){
        for (int i = 0; i < n; i += 4){
          int ids[4];
          #pragma unroll
          for (int j = 0; j < 4; ++j){
            int t2 = i + j; t2 = (t2 < n) ? t2 : (n - 1);
            ids[j] = (int)Es[rel + t2];
          }
          uint4 bu[4];
          #pragma unroll
          for (int j = 0; j < 4; ++j)
            bu[j] = *reinterpret_cast<const uint4*>(&Bm[(size_t)ids[j]*GH + 16*c]);
          #pragma unroll
          for (int j = 0; j < 4; ++j){
            float live = (i + j < n) ? 1.f : 0.f;
            #pragma unroll
            for (int wq = 0; wq < 4; ++wq)
              acc_u32((&bu[j].x)[wq], ax + wq*4, s + wq*4, live);
          }
        }
      } else {
        for (int i = 0; i < n; i += 4){
          int ids[4];
          #pragma unroll
          for (int j = 0; j < 4; ++j){
            int t2 = i + j; t2 = (t2 < n) ? t2 : (n - 1);
            ids[j] = (int)ssrc[beg + t2];
          }
          uint4 bu[4];
          #pragma unroll
          for (int j = 0; j < 4; ++j)
            bu[j] = *reinterpret_cast<const uint4*>(&Bm[(size_t)ids[j]*GH + 16*c]);
          #pragma unroll
          for (int j = 0; j < 4; ++j){
            float live = (i + j < n) ? 1.f : 0.f;
            #pragma unroll
            for (int wq = 0; wq < 4; ++wq)
              acc_u32((&bu[j].x)[wq], ax + wq*4, s + wq*4, live);
          }
        }
      }
    }
    uint4 o;
    o.x = (unsigned)pk2bf(s[0], s[1]);   o.y = (unsigned)pk2bf(s[2], s[3]);
    o.z = (unsigned)pk2bf(s[4], s[5]);   o.w = (unsigned)pk2bf(s[6], s[7]);
    *reinterpret_cast<uint4*>(&Hs1[vloc*HSS + 16*c]) = o;
    o.x = (unsigned)pk2bf(s[8], s[9]);   o.y = (unsigned)pk2bf(s[10], s[11]);
    o.z = (unsigned)pk2bf(s[12], s[13]); o.w = (unsigned)pk2bf(s[14], s[15]);
    *reinterpret_cast<uint4*>(&Hs1[vloc*HSS + 16*c + 8]) = o;
  }
  __syncthreads();                      // Es dead after this point

  // ---- GEMM1: Hs1 @ W2t -> h (mean+bias+relu) -> Hs2.  2 waves: 16 rows, cols 64x2
  int w = tid >> 6, lane = tid & 63, l15 = tid & 15, quad = lane >> 4;
  int cb = w * 64;
  f32x4 acc[4];
  #pragma unroll
  for (int t = 0; t < 4; ++t) acc[t] = (f32x4){0.f,0.f,0.f,0.f};
  #pragma unroll
  for (int k0 = 0; k0 < 128; k0 += 32){
    short8v ah = *reinterpret_cast<short8v*>(&Hs1[l15*HSS + k0 + quad*8]);
    #pragma unroll
    for (int t = 0; t < 4; ++t){
      short8v bh = *reinterpret_cast<const short8v*>(&W2t[(cb + t*16 + l15)*GH + k0 + quad*8]);
      acc[t] = __builtin_amdgcn_mfma_f32_16x16x32_bf16(ah, bh, acc[t], 0, 0, 0);
    }
  }
  __syncthreads();                      // all Es reads done before Hs2 writes
  #pragma unroll
  for (int r = 0; r < 4; ++r){
    int ml = quad*4 + r;                // 0..15
    int m = m0 + ml;
    float fcnt = (float)cnt[m];
    float inv = 1.f / fmaxf(fcnt, 1.f);
    #pragma unroll
    for (int t = 0; t < 4; ++t){
      int col = cb + t*16 + l15;
      float v = (acc[t][r] + fcnt * b2[col]) * inv;
      Hs2[ml*HSS + col] = f2bf(fmaxf(v, 0.f));
    }
  }
  __syncthreads();

  // ---- GEMM2: Hs2 @ W3t -> fp8 fC|fD ----
  f32x4 acc2[4];
  #pragma unroll
  for (int t = 0; t < 4; ++t) acc2[t] = (f32x4){0.f,0.f,0.f,0.f};
  #pragma unroll
  for (int k0 = 0; k0 < 128; k0 += 32){
    short8v ah = *reinterpret_cast<short8v*>(&Hs2[l15*HSS + k0 + quad*8]);
    #pragma unroll
    for (int t = 0; t < 4; ++t){
      short8v bh = *reinterpret_cast<const short8v*>(&W3t[(cb + t*16 + l15)*GH + k0 + quad*8]);
      acc2[t] = __builtin_amdgcn_mfma_f32_16x16x32_bf16(ah, bh, acc2[t], 0, 0, 0);
    }
  }
  #pragma unroll
  for (int r = 0; r < 4; ++r){
    int m = m0 + quad*4 + r;
    #pragma unroll
    for (int t = 0; t < 4; ++t){
      int col = cb + t*16 + l15;
      unsigned char o = f32_to_fp8(acc2[t][r]);
      if (col < 64) fC[(size_t)m*GD + col] = o;
      else          fD[(size_t)m*GD + col - 64] = o;
    }
  }
}

// ---- fused2 (16-row tile, 128 thr): edge-agg L2 -> GEMM(W4t)+mean -> graph-sum ----
__global__ __launch_bounds__(128)
void k_fused2(const unsigned char* __restrict__ C, const unsigned char* __restrict__ D,
              const float* __restrict__ b1, const int* __restrict__ offs,
              const int* __restrict__ cnt, const unsigned short* __restrict__ ssrc,
              const unsigned short* __restrict__ W4t, const float* __restrict__ bias,
              const int* __restrict__ nb, float* __restrict__ gsum)
{
  __shared__ unsigned short As[QB*ASS];  // gather result tile, bf16 (2304 B)
  __shared__ float TsEs[QB*65];          // union: Es (phase A) / Ts (epilogue), 4160 B
  unsigned short* Es = reinterpret_cast<unsigned short*>(TsEs);  // 2048 u16 = 4096 B
  float* Ts = TsEs;
  int tid = threadIdx.x;
  int m0 = blockIdx.x*QB;

  int beg0 = offs[m0];
  int end0 = offs[m0 + QB];
  int nwin = end0 - beg0;
  for (int i = tid; i < nwin && i < ECAP; i += 128)
    Es[i] = ssrc[beg0 + i];
  __syncthreads();

  // ---- phase A: edge aggregation, 16 nodes x 8 lanes x 8 ch ----
  {
    int vloc = tid >> 3;
    int v = m0 + vloc;
    int c = tid & 7;                  // channels 8c .. 8c+7
    float s[8];
    #pragma unroll
    for (int q = 0; q < 8; ++q) s[q] = 0.f;
    int beg = offs[v], n = cnt[v];
    if (n > 0){
      int rel = beg - beg0;
      uint2 au = *reinterpret_cast<const uint2*>(&C[(size_t)v*GD + 8*c]);
      float ax[8];
      #pragma unroll
      for (int wq = 0; wq < 2; ++wq){
        unsigned u = (&au.x)[wq];
        f32x2 p0 = fp8x2_to_f32((unsigned short)(u & 0xFFFFu));
        f32x2 p1 = fp8x2_to_f32((unsigned short)(u >> 16));
        float4 bb = *reinterpret_cast<const float4*>(&b1[8*c + 4*wq]);
        ax[wq*4+0] = p0.x + bb.x; ax[wq*4+1] = p0.y + bb.y;
        ax[wq*4+2] = p1.x + bb.z; ax[wq*4+3] = p1.y + bb.w;
      }
      bool fits = (rel + n) <= ECAP;
      if (fits){
        for (int i = 0; i < n; i += 4){
          int ids[4];
          #pragma unroll
          for (int j = 0; j < 4; ++j){
            int t2 = i + j; t2 = (t2 < n) ? t2 : (n - 1);
            ids[j] = (int)Es[rel + t2];
          }
          uint2 du[4];
          #pragma unroll
          for (int j = 0; j < 4; ++j)
            du[j] = *reinterpret_cast<const uint2*>(&D[(size_t)ids[j]*GD + 8*c]);
          #pragma unroll
          for (int j = 0; j < 4; ++j){
            float live = (i + j < n) ? 1.f : 0.f;
            #pragma unroll
            for (int wq = 0; wq < 2; ++wq)
              acc_u32((&du[j].x)[wq], ax + wq*4, s + wq*4, live);
          }
        }
      } else {
        for (int i = 0; i < n; i += 4){
          int ids[4];
          #pragma unroll
          for (int j = 0; j < 4; ++j){
            int t2 = i + j; t2 = (t2 < n) ? t2 : (n - 1);
            ids[j] = (int)ssrc[beg + t2];
          }
          uint2 du[4];
          #pragma unroll
          for (int j = 0; j < 4; ++j)
            du[j] = *reinterpret_cast<const uint2*>(&D[(size_t)ids[j]*GD + 8*c]);
          #pragma unroll
          for (int j = 0; j < 4; ++j){
            float live = (i + j < n) ? 1.f : 0.f;
            #pragma unroll
            for (int wq = 0; wq < 2; ++wq)
              acc_u32((&du[j].x)[wq], ax + wq*4, s + wq*4, live);
          }
        }
      }
    }
    uint4 o;
    o.x = (unsigned)pk2bf(s[0], s[1]); o.y = (unsigned)pk2bf(s[2], s[3]);
    o.z = (unsigned)pk2bf(s[4], s[5]); o.w = (unsigned)pk2bf(s[6], s[7]);
    *reinterpret_cast<uint4*>(&As[vloc*ASS + 8*c]) = o;
  }
  __syncthreads();

  // ---- GEMM: As @ W4t, mean + bias.  2 waves: 16 rows, cols 32x2 ----
  int w = tid >> 6, lane = tid & 63, l15 = tid & 15, quad = lane >> 4;
  int cb = w * 32;
  f32x4 acc[2];
  #pragma unroll
  for (int t = 0; t < 2; ++t) acc[t] = (f32x4){0.f,0.f,0.f,0.f};
  #pragma unroll
  for (int k0 = 0; k0 < 64; k0 += 32){
    short8v ah = *reinterpret_cast<short8v*>(&As[l15*ASS + k0 + quad*8]);
    #pragma unroll
    for (int t = 0; t < 2; ++t){
      short8v bh = *reinterpret_cast<const short8v*>(&W4t[(cb + t*16 + l15)*GD + k0 + quad*8]);
      acc[t] = __builtin_amdgcn_mfma_f32_16x16x32_bf16(ah, bh, acc[t], 0, 0, 0);
    }
  }
  __syncthreads();                      // all Es reads done before Ts writes
  #pragma unroll
  for (int r = 0; r < 4; ++r){
    int ml = quad*4 + r;                // 0..15
    int m = m0 + ml;
    float fcnt = (float)cnt[m];
    float inv = 1.f / fmaxf(fcnt, 1.f);
    #pragma unroll
    for (int t = 0; t < 2; ++t){
      int n = cb + t*16 + l15;
      Ts[ml*65 + n] = (acc[t][r] + fcnt * bias[n]) * inv;
    }
  }
  __syncthreads();
  int col = tid & 63, rg = tid >> 6;    // rg 0..1, 8 rows each
  float a = 0.f; int cur = -1;
  for (int rr = rg*8; rr < rg*8 + 8; ++rr){
    int m = m0 + rr;
    int g = nb[m];
    if (g != cur){ if (cur >= 0) atomicAdd(&gsum[cur*GD + col], a); cur = g; a = 0.f; }
    a += Ts[rr*65 + col];
  }
  if (cur >= 0) atomicAdd(&gsum[cur*GD + col], a);
}

// ---------------- actor head: one block per batch row (divide fused here) -----
__global__ __launch_bounds__(256)
void k_head(const float* __restrict__ state, const float* __restrict__ gsum,
            const int* __restrict__ nb,
            const float* __restrict__ fc1w, const float* __restrict__ fc1b,
            const float* __restrict__ fc2w, const float* __restrict__ fc2b,
            const float* __restrict__ mw, const float* __restrict__ mb,
            const float* __restrict__ lw, const float* __restrict__ lb,
            float* __restrict__ out)
{
  int b = blockIdx.x, t = threadIdx.x;
  __shared__ float z[SD + GD];
  __shared__ float h1[HID];
  __shared__ float h2[HID];
  __shared__ float part[16][17];
  __shared__ int bounds[2];
  if (t < 2){
    int target = b + t;
    int lo = 0, hi = NN;
    while (lo < hi){ int mid = (lo + hi) >> 1; if (nb[mid] < target) lo = mid + 1; else hi = mid; }
    bounds[t] = lo;
  }
  if (t < SD) z[t] = state[b*SD + t];
  __syncthreads();
  if (t >= SD && t < SD + GD){
    float n = (float)(bounds[1] - bounds[0]);
    z[t] = gsum[b*GD + (t - SD)] / fmaxf(n, 1.f);
  }
  __syncthreads();
  float a0 = 0.f, a1 = 0.f;
  #pragma unroll 4
  for (int k = 0; k < SD + GD; k += 2){
    a0 = fmaf(z[k],   fc1w[k*HID + t],     a0);
    a1 = fmaf(z[k+1], fc1w[(k+1)*HID + t], a1);
  }
  h1[t] = fmaxf(a0 + a1 + fc1b[t], 0.f);
  __syncthreads();
  float t0 = 0.f, t1 = 0.f, t2 = 0.f, t3 = 0.f;
  #pragma unroll 4
  for (int k = 0; k < HID; k += 4){
    t0 = fmaf(h1[k],   fc2w[k*HID + t],     t0);
    t1 = fmaf(h1[k+1], fc2w[(k+1)*HID + t], t1);
    t2 = fmaf(h1[k+2], fc2w[(k+2)*HID + t], t2);
    t3 = fmaf(h1[k+3], fc2w[(k+3)*HID + t], t3);
  }
  h2[t] = fmaxf((t0 + t1) + (t2 + t3) + fc2b[t], 0.f);
  __syncthreads();
  { int j = t & 15, p = t >> 4;
    const float* wv = (j < 8) ? mw : lw;
    int colj = j & 7;
    float a = 0.f;
    #pragma unroll
    for (int k = 0; k < 16; ++k)
      a = fmaf(h2[p*16 + k], wv[(p*16 + k)*AD + colj], a);
    part[p][j] = a;
  }
  __syncthreads();
  if (t < 16){
    float sum = (t < 8) ? mb[t] : lb[t - 8];
    #pragma unroll
    for (int p2 = 0; p2 < 16; ++p2) sum += part[p2][t];
    if (t < 8) out[b*AD + t] = sum;
    else       out[NB*AD + b*AD + (t - 8)] = fminf(fmaxf(sum, -20.f), 2.f);
  }
}

extern "C" void kernel_launch(void* const* d_in, const int* in_sizes, int n_in,
                              void* d_out, int out_size, void* d_ws, size_t ws_size,
                              hipStream_t stream)
{
  const float* state = (const float*)d_in[0];
  const float* x     = (const float*)d_in[1];
  const int*   eidx  = (const int*)  d_in[2];
  const int*   nb    = (const int*)  d_in[3];
  const float* g1w1  = (const float*)d_in[4];
  const float* g1b1  = (const float*)d_in[5];
  const float* g1w2  = (const float*)d_in[6];
  const float* g1b2  = (const float*)d_in[7];
  const float* g2w1  = (const float*)d_in[8];
  const float* g2b1  = (const float*)d_in[9];
  const float* g2w2  = (const float*)d_in[10];
  const float* g2b2  = (const float*)d_in[11];
  const float* fc1w  = (const float*)d_in[12];
  const float* fc1b  = (const float*)d_in[13];
  const float* fc2w  = (const float*)d_in[14];
  const float* fc2b  = (const float*)d_in[15];
  const float* mw    = (const float*)d_in[16];
  const float* mb    = (const float*)d_in[17];
  const float* lw    = (const float*)d_in[18];
  const float* lb    = (const float*)d_in[19];

  const int* e_src = eidx;        // edge_index[0]
  const int* e_dst = eidx + NE;   // edge_index[1]

  char* p = (char*)d_ws;
  auto alloc = [&](size_t bytes){ char* r = p; p += align256(bytes); return r; };
  int*   cnt8   = (int*)  alloc((size_t)NP*CPAD*4); // partial hists; contiguous w/ gsum
  float* gsum   = (float*)alloc((size_t)NB*GD*4);
  int*   cnt    = (int*)  alloc((size_t)CPAD*4);    // totals (written by scan)
  int*   offs   = (int*)  alloc((size_t)CPAD*4);
  int*   offs8  = (int*)  alloc((size_t)NP*CPAD*4); // per-partition bases
  unsigned short* rank = (unsigned short*)alloc((size_t)NE*2);
  unsigned short* ssrc = (unsigned short*)alloc((size_t)NE*2);
  unsigned char*  fA8 = (unsigned char*) alloc((size_t)NN2*GH);    // fp8 [NN2,128]
  unsigned char*  fB8 = (unsigned char*) alloc((size_t)NN2*GH);    // fp8 [NN2,128]
  unsigned char*  fC8 = (unsigned char*) alloc((size_t)NN*GD);     // fp8 [NN,64]
  unsigned char*  fD8 = (unsigned char*) alloc((size_t)NN*GD);     // fp8 [NN,64]
  unsigned short* W2t = (unsigned short*)alloc((size_t)GH*GH*2);   // bf16 [128][128] (n,k)
  unsigned short* W3t = (unsigned short*)alloc((size_t)GH*GH*2);   // bf16 [128][128] (n,k)
  unsigned short* W4t = (unsigned short*)alloc((size_t)GD*GD*2);   // bf16 [64][64]  (n,k)

  hipMemsetAsync(cnt8, 0, (size_t)NP*CPAD*4 + (size_t)NB*GD*4, stream);

  dim3 b256(256), b128(128);
  k_pre<<<dim3(EB + MB*2 + NCV), b256, 0, stream>>>(e_dst, cnt8, rank, x, g1w1, fA8, fB8,
                                                    g1w2, g2w1, g2w2, W2t, W3t, W4t);
  k_scan1 <<<dim3(1), dim3(1024), 0, stream>>>(cnt8, cnt, offs, offs8);
  k_place <<<dim3(EB), b256, 0, stream>>>(e_src, e_dst, offs8, rank, ssrc);

  k_fused1<<<dim3(NT), b128, 0, stream>>>(fA8, fB8, g1b1, offs, cnt, ssrc,
                                          W2t, W3t, g1b2, fC8, fD8);
  k_fused2<<<dim3(NT), b128, 0, stream>>>(fC8, fD8, g2b1, offs, cnt, ssrc,
                                          W4t, g2b2, nb, gsum);
  k_head<<<dim3(NB), b256, 0, stream>>>(state, gsum, nb, fc1w, fc1b, fc2w, fc2b,
                                        mw, mb, lw, lb, (float*)d_out);
}

// Round 16
// 233.541 us; speedup vs baseline: 2.2950x; 1.8013x over previous
//
#include <hip/hip_runtime.h>

#define NN 50000      // nodes
#define NN2 50048     // nodes padded to 64
#define NE 800000     // edges
#define NB 128        // graphs / batch
#define SD 64         // state dim / node dim
#define GH 128        // gnn layer1 width
#define GD 64         // gnn layer2 width
#define HID 256       // actor hidden
#define AD 8          // action dim
#define CPAD 53248    // cnt/offs padded: 1024*52
#define NP 8          // hist partitions
#define SB 52         // scan blocks (CPAD/1024)
#define EB 391        // edge blocks (2048 edges each)
#define MB 782        // 64-row m-tiles (k_pre gemm)
#define NCV 48        // weight-convert blocks (16 per weight)
#define NT 3125       // 16-row tiles (fused kernels), 50000/16 exactly
#define QB 16         // rows per fused tile
#define ECAP 2048     // LDS edge-window capacity (u16); mean 256, huge headroom
#define BST2 130      // wide B-tile stride (shorts), 65 ints
#define TSS 132       // f32 transpose-buffer stride (16B-aligned rows)
#define HSS 136       // Hs row stride (shorts), 272B = 17*16B
#define ASS 72        // As row stride (shorts), 144B = 9*16B

static inline size_t align256(size_t x){ return (x + 255) & ~size_t(255); }

typedef __attribute__((ext_vector_type(8))) short short8v;
typedef __attribute__((ext_vector_type(4))) float f32x4;
typedef __attribute__((ext_vector_type(2))) float f32x2;

__device__ inline unsigned short f2bf(float f){  // RNE
  unsigned u = __builtin_bit_cast(unsigned, f);
  return (unsigned short)((u + 0x7FFFu + ((u >> 16) & 1u)) >> 16);
}
__device__ inline int pk2bf(float a, float b){
  return (int)((unsigned)f2bf(a) | ((unsigned)f2bf(b) << 16));
}
// fp8 e4m3 HW converts
__device__ inline f32x2 fp8x2_to_f32(unsigned short u){
  return __builtin_amdgcn_cvt_pk_f32_fp8((int)u, false);
}
__device__ inline unsigned char f32_to_fp8(float v){
  return (unsigned char)(__builtin_amdgcn_cvt_pk_fp8_f32(v, v, 0, false) & 0xFF);
}
__device__ inline unsigned pack4_fp8(float a, float b, float c, float d){
  int w = __builtin_amdgcn_cvt_pk_fp8_f32(a, b, 0, false);
  w = __builtin_amdgcn_cvt_pk_fp8_f32(c, d, w, true);
  return (unsigned)w;
}
// accumulate 4 fp8 channels of one edge row word
__device__ inline void acc_u32(unsigned u, const float* ax, float* s, float live){
  f32x2 p0 = fp8x2_to_f32((unsigned short)(u & 0xFFFFu));
  f32x2 p1 = fp8x2_to_f32((unsigned short)(u >> 16));
  s[0] = fmaf(live, fmaxf(ax[0] + p0.x, 0.f), s[0]);
  s[1] = fmaf(live, fmaxf(ax[1] + p0.y, 0.f), s[1]);
  s[2] = fmaf(live, fmaxf(ax[2] + p1.x, 0.f), s[2]);
  s[3] = fmaf(live, fmaxf(ax[3] + p1.y, 0.f), s[3]);
}

// ---- dispatch 1: hist [0,EB) ∥ layer-1 GEMM [EB,EB+2*MB) ∥ weight-convert (48) ----
// hist: 8-WAY PARTIAL histograms (partition = blockIdx&7) -> 8x less line contention.
__global__ __launch_bounds__(256)
void k_pre(const int* __restrict__ edst, int* __restrict__ cnt8,
           unsigned short* __restrict__ rank,
           const float* __restrict__ x, const float* __restrict__ w1,
           unsigned char* __restrict__ fA8, unsigned char* __restrict__ fB8,
           const float* __restrict__ w2, const float* __restrict__ w3,
           const float* __restrict__ w4,
           unsigned short* __restrict__ W2t, unsigned short* __restrict__ W3t,
           unsigned short* __restrict__ W4t)
{
  int tid = threadIdx.x;
  if (blockIdx.x < EB){
    int* cp = cnt8 + (size_t)(blockIdx.x & (NP-1))*CPAD;
    int e = blockIdx.x*2048 + tid;
    #pragma unroll
    for (int j = 0; j < 8; ++j){
      int ee = e + j*256;
      if (ee < NE) rank[ee] = (unsigned short)atomicAdd(&cp[edst[ee]], 1);
    }
    return;
  }
  int idx = blockIdx.x - EB;
  if (idx >= 2*MB){                    // weight-convert blocks (coalesced writes)
    int widx = idx - 2*MB;
    int wb = widx >> 4, sub = widx & 15;
    if (wb == 0){                      // W2t[n][k] = w2[k][n], 128x128
      #pragma unroll
      for (int i = 0; i < 4; ++i){
        int o = sub*1024 + tid + i*256;
        int n = o >> 7, k = o & 127;
        W2t[o] = f2bf(w2[k*GH + n]);
      }
    } else if (wb == 1){               // W3t[n][k]; n<64 from w3 rows 0..127, else 128..255
      #pragma unroll
      for (int i = 0; i < 4; ++i){
        int o = sub*1024 + tid + i*256;
        int n = o >> 7, k = o & 127;
        int row = k + ((n >= 64) ? 128 : 0);
        int col = n & 63;
        W3t[o] = f2bf(w3[row*GD + col]);
      }
    } else {                           // W4t[n][k] = w4[k][n], 64x64
      int o = sub*256 + tid;
      int n = o >> 6, k = o & 63;
      W4t[o] = f2bf(w4[k*GD + n]);
    }
    return;
  }
  int m0 = (idx >> 1) * 64;
  int z  = idx & 1;
  const float* W = w1 + (size_t)z*64*GH;
  unsigned char* Out = z ? fB8 : fA8;

  __shared__ float Ts[64*TSS];               // 33.8 KB; aliased by stage bufs
  short* Ah = reinterpret_cast<short*>(Ts);  // [64][40]
  short* Bh = Ah + 64*40;                    // [32][BST2]

  int w = tid >> 6, lane = tid & 63, l15 = tid & 15, quad = lane >> 4;
  f32x4 acc[8];
  #pragma unroll
  for (int t = 0; t < 8; ++t) acc[t] = (f32x4){0.f,0.f,0.f,0.f};

  #pragma unroll
  for (int k0 = 0; k0 < 64; k0 += 32){
    { // A: x fp32 -> bf16, 64 rows x 32 k
      int m = tid >> 2, q = tid & 3;
      float4 v0 = make_float4(0.f,0.f,0.f,0.f), v1 = v0;
      if (m0 + m < NN){
        const float* xr = &x[(size_t)(m0+m)*SD + k0 + q*8];
        v0 = *reinterpret_cast<const float4*>(xr);
        v1 = *reinterpret_cast<const float4*>(xr + 4);
      }
      int4 h;
      h.x = pk2bf(v0.x, v0.y); h.y = pk2bf(v0.z, v0.w);
      h.z = pk2bf(v1.x, v1.y); h.w = pk2bf(v1.z, v1.w);
      *reinterpret_cast<int4*>(&Ah[m*40 + q*8]) = h;
    }
    #pragma unroll
    for (int i = 0; i < 4; ++i){       // B: W fp32 -> bf16 [k][n], 128 cols
      int s = tid + i*256;
      int r = s >> 5, cq = s & 31;
      float4 v = *reinterpret_cast<const float4*>(&W[(size_t)(k0+r)*GH + cq*4]);
      *reinterpret_cast<int*>(&Bh[r*BST2 + cq*4])     = pk2bf(v.x, v.y);
      *reinterpret_cast<int*>(&Bh[r*BST2 + cq*4 + 2]) = pk2bf(v.z, v.w);
    }
    __syncthreads();
    short8v ah = *reinterpret_cast<short8v*>(&Ah[(w*16 + l15)*40 + quad*8]);
    #pragma unroll
    for (int t = 0; t < 8; ++t){
      short8v bh;
      #pragma unroll
      for (int j = 0; j < 8; ++j)
        bh[j] = Bh[(quad*8 + j)*BST2 + t*16 + l15];
      acc[t] = __builtin_amdgcn_mfma_f32_16x16x32_bf16(ah, bh, acc[t], 0, 0, 0);
    }
    __syncthreads();
  }
  #pragma unroll
  for (int r = 0; r < 4; ++r){
    int ml = w*16 + quad*4 + r;
    #pragma unroll
    for (int t = 0; t < 8; ++t)
      Ts[ml*TSS + t*16 + l15] = acc[t][r];
  }
  __syncthreads();
  int row = tid >> 2, seg = tid & 3;
  const float4* tr4 = reinterpret_cast<const float4*>(&Ts[row*TSS + seg*32]);
  float4 f0 = tr4[0], f1 = tr4[1], f2 = tr4[2], f3 = tr4[3];
  uint4 o;
  o.x = pack4_fp8(f0.x,f0.y,f0.z,f0.w);
  o.y = pack4_fp8(f1.x,f1.y,f1.z,f1.w);
  o.z = pack4_fp8(f2.x,f2.y,f2.z,f2.w);
  o.w = pack4_fp8(f3.x,f3.y,f3.z,f3.w);
  *reinterpret_cast<uint4*>(&Out[(size_t)(m0+row)*GH + seg*32]) = o;
  float4 f4 = tr4[4], f5 = tr4[5], f6 = tr4[6], f7 = tr4[7];
  o.x = pack4_fp8(f4.x,f4.y,f4.z,f4.w);
  o.y = pack4_fp8(f5.x,f5.y,f5.z,f5.w);
  o.z = pack4_fp8(f6.x,f6.y,f6.z,f6.w);
  o.w = pack4_fp8(f7.x,f7.y,f7.z,f7.w);
  *reinterpret_cast<uint4*>(&Out[(size_t)(m0+row)*GH + seg*32 + 16]) = o;
}

// ---- scan A: 52 blocks x 1024 thr, 1 node/thread. Coalesced partition sums,
// block-local exclusive prefix, per-block sum. ----
__global__ __launch_bounds__(1024)
void k_scanA(const int* __restrict__ cnt8, int* __restrict__ tot,
             int* __restrict__ npfx, int* __restrict__ bsum){
  __shared__ int sm[1024];
  int t = threadIdx.x;
  int v = blockIdx.x*1024 + t;
  int s = 0;
  #pragma unroll
  for (int p = 0; p < NP; ++p) s += cnt8[(size_t)p*CPAD + v];   // coalesced
  sm[t] = s; __syncthreads();
  for (int d = 1; d < 1024; d <<= 1){
    int add = (t >= d) ? sm[t - d] : 0;
    __syncthreads();
    sm[t] += add;
    __syncthreads();
  }
  tot[v]  = s;
  npfx[v] = sm[t] - s;           // exclusive within block
  if (t == 1023) bsum[blockIdx.x] = sm[t];
}

// ---- scan B: 52 blocks x 1024 thr. Block base from bsum prefix (LDS), then
// coalesced writes of offs / cnt / 8x offs8 planes. ----
__global__ __launch_bounds__(1024)
void k_scanB(const int* __restrict__ cnt8, const int* __restrict__ tot,
             const int* __restrict__ npfx, const int* __restrict__ bsum,
             int* __restrict__ cnt, int* __restrict__ offs, int* __restrict__ offs8){
  __shared__ int bs[SB];
  __shared__ int base;
  int t = threadIdx.x, b = blockIdx.x;
  if (t < SB) bs[t] = bsum[t];
  __syncthreads();
  if (t == 0){
    int s = 0;
    for (int i = 0; i < b; ++i) s += bs[i];
    base = s;
  }
  __syncthreads();
  int v = b*1024 + t;
  int c8[NP];
  #pragma unroll
  for (int p = 0; p < NP; ++p) c8[p] = cnt8[(size_t)p*CPAD + v];  // coalesced
  int run = base + npfx[v];
  offs[v] = run;
  cnt[v]  = tot[v];
  #pragma unroll
  for (int p = 0; p < NP; ++p){
    offs8[(size_t)p*CPAD + v] = run;                              // coalesced
    run += c8[p];
  }
}

// place: independent scatter (partition base + within-partition rank)
__global__ void k_place(const int* __restrict__ esrc, const int* __restrict__ edst,
                        const int* __restrict__ offs8,
                        const unsigned short* __restrict__ rank,
                        unsigned short* __restrict__ ssrc){
  const int* op = offs8 + (size_t)(blockIdx.x & (NP-1))*CPAD;
  int e = blockIdx.x*2048 + threadIdx.x;
  #pragma unroll
  for (int j = 0; j < 8; ++j){
    int ee = e + j*256;
    if (ee < NE) ssrc[op[edst[ee]] + (int)rank[ee]] = (unsigned short)esrc[ee];
  }
}

// ---- fused1 (16-row tile, 128 thr): edge-agg L1 -> GEMM(W2t) -> GEMM(W3t) -> fp8 ----
__global__ __launch_bounds__(128)
void k_fused1(const unsigned char* __restrict__ A, const unsigned char* __restrict__ Bm,
              const float* __restrict__ b1, const int* __restrict__ offs,
              const int* __restrict__ cnt, const unsigned short* __restrict__ ssrc,
              const unsigned short* __restrict__ W2t, const unsigned short* __restrict__ W3t,
              const float* __restrict__ b2,
              unsigned char* __restrict__ fC, unsigned char* __restrict__ fD)
{
  __shared__ unsigned short Hs1[QB*HSS];     // gather result tile, bf16 (4352 B)
  __shared__ unsigned short EsHs2[QB*HSS];   // union: Es (phase A) / Hs2 (after GEMM1)
  unsigned short* Es  = EsHs2;               // ECAP=2048 u16 = 4096 B <= 4352 B
  unsigned short* Hs2 = EsHs2;
  int tid = threadIdx.x;
  int m0 = blockIdx.x*QB;

  int beg0 = offs[m0];
  int end0 = offs[m0 + QB];
  int nwin = end0 - beg0;
  for (int i = tid; i < nwin && i < ECAP; i += 128)
    Es[i] = ssrc[beg0 + i];
  __syncthreads();

  // ---- phase A: edge aggregation, 16 nodes x 8 lanes x 16 ch ----
  {
    int vloc = tid >> 3;              // 0..15
    int v = m0 + vloc;                // < NN always (NN % 16 == 0)
    int c = tid & 7;                  // channels 16c .. 16c+15
    float s[16];
    #pragma unroll
    for (int q = 0; q < 16; ++q) s[q] = 0.f;
    int beg = offs[v], n = cnt[v];
    if (n > 0){
      int rel = beg - beg0;
      uint4 au = *reinterpret_cast<const uint4*>(&A[(size_t)v*GH + 16*c]);
      float ax[16];
      #pragma unroll
      for (int wq = 0; wq < 4; ++wq){
        unsigned u = (&au.x)[wq];
        f32x2 p0 = fp8x2_to_f32((unsigned short)(u & 0xFFFFu));
        f32x2 p1 = fp8x2_to_f32((unsigned short)(u >> 16));
        float4 bb = *reinterpret_cast<const float4*>(&b1[16*c + 4*wq]);
        ax[wq*4+0] = p0.x + bb.x; ax[wq*4+1] = p0.y + bb.y;
        ax[wq*4+2] = p1.x + bb.z; ax[wq*4+3] = p1.y + bb.w;
      }
      bool fits = (rel + n) <= ECAP;    // ~always true
      if (fits){
        for (int i = 0; i < n; i += 4){
          int ids[4];
          #pragma unroll
          for (int j = 0; j < 4; ++j){
            int t2 = i + j; t2 = (t2 < n) ? t2 : (n - 1);
            ids[j] = (int)Es[rel + t2];
          }
          uint4 bu[4];
          #pragma unroll
          for (int j = 0; j < 4; ++j)
            bu[j] = *reinterpret_cast<const uint4*>(&Bm[(size_t)ids[j]*GH + 16*c]);
          #pragma unroll
          for (int j = 0; j < 4; ++j){
            float live = (i + j < n) ? 1.f : 0.f;
            #pragma unroll
            for (int wq = 0; wq < 4; ++wq)
              acc_u32((&bu[j].x)[wq], ax + wq*4, s + wq*4, live);
          }
        }
      } else {
        for (int i = 0; i < n; i += 4){
          int ids[4];
          #pragma unroll
          for (int j = 0; j < 4; ++j){
            int t2 = i + j; t2 = (t2 < n) ? t2 : (n - 1);
            ids[j] = (int)ssrc[beg + t2];
          }
          uint4 bu[4];
          #pragma unroll
          for (int j = 0; j < 4; ++j)
            bu[j] = *reinterpret_cast<const uint4*>(&Bm[(size_t)ids[j]*GH + 16*c]);
          #pragma unroll
          for (int j = 0; j < 4; ++j){
            float live = (i + j < n) ? 1.f : 0.f;
            #pragma unroll
            for (int wq = 0; wq < 4; ++wq)
              acc_u32((&bu[j].x)[wq], ax + wq*4, s + wq*4, live);
          }
        }
      }
    }
    uint4 o;
    o.x = (unsigned)pk2bf(s[0], s[1]);   o.y = (unsigned)pk2bf(s[2], s[3]);
    o.z = (unsigned)pk2bf(s[4], s[5]);   o.w = (unsigned)pk2bf(s[6], s[7]);
    *reinterpret_cast<uint4*>(&Hs1[vloc*HSS + 16*c]) = o;
    o.x = (unsigned)pk2bf(s[8], s[9]);   o.y = (unsigned)pk2bf(s[10], s[11]);
    o.z = (unsigned)pk2bf(s[12], s[13]); o.w = (unsigned)pk2bf(s[14], s[15]);
    *reinterpret_cast<uint4*>(&Hs1[vloc*HSS + 16*c + 8]) = o;
  }
  __syncthreads();                      // Es dead after this point

  // ---- GEMM1: Hs1 @ W2t -> h (mean+bias+relu) -> Hs2.  2 waves: 16 rows, cols 64x2
  int w = tid >> 6, lane = tid & 63, l15 = tid & 15, quad = lane >> 4;
  int cb = w * 64;
  f32x4 acc[4];
  #pragma unroll
  for (int t = 0; t < 4; ++t) acc[t] = (f32x4){0.f,0.f,0.f,0.f};
  #pragma unroll
  for (int k0 = 0; k0 < 128; k0 += 32){
    short8v ah = *reinterpret_cast<short8v*>(&Hs1[l15*HSS + k0 + quad*8]);
    #pragma unroll
    for (int t = 0; t < 4; ++t){
      short8v bh = *reinterpret_cast<const short8v*>(&W2t[(cb + t*16 + l15)*GH + k0 + quad*8]);
      acc[t] = __builtin_amdgcn_mfma_f32_16x16x32_bf16(ah, bh, acc[t], 0, 0, 0);
    }
  }
  __syncthreads();                      // all Es reads done before Hs2 writes
  #pragma unroll
  for (int r = 0; r < 4; ++r){
    int ml = quad*4 + r;                // 0..15
    int m = m0 + ml;
    float fcnt = (float)cnt[m];
    float inv = 1.f / fmaxf(fcnt, 1.f);
    #pragma unroll
    for (int t = 0; t < 4; ++t){
      int col = cb + t*16 + l15;
      float v = (acc[t][r] + fcnt * b2[col]) * inv;
      Hs2[ml*HSS + col] = f2bf(fmaxf(v, 0.f));
    }
  }
  __syncthreads();

  // ---- GEMM2: Hs2 @ W3t -> fp8 fC|fD ----
  f32x4 acc2[4];
  #pragma unroll
  for (int t = 0; t < 4; ++t) acc2[t] = (f32x4){0.f,0.f,0.f,0.f};
  #pragma unroll
  for (int k0 = 0; k0 < 128; k0 += 32){
    short8v ah = *reinterpret_cast<short8v*>(&Hs2[l15*HSS + k0 + quad*8]);
    #pragma unroll
    for (int t = 0; t < 4; ++t){
      short8v bh = *reinterpret_cast<const short8v*>(&W3t[(cb + t*16 + l15)*GH + k0 + quad*8]);
      acc2[t] = __builtin_amdgcn_mfma_f32_16x16x32_bf16(ah, bh, acc2[t], 0, 0, 0);
    }
  }
  #pragma unroll
  for (int r = 0; r < 4; ++r){
    int m = m0 + quad*4 + r;
    #pragma unroll
    for (int t = 0; t < 4; ++t){
      int col = cb + t*16 + l15;
      unsigned char o = f32_to_fp8(acc2[t][r]);
      if (col < 64) fC[(size_t)m*GD + col] = o;
      else          fD[(size_t)m*GD + col - 64] = o;
    }
  }
}

// ---- fused2 (16-row tile, 128 thr): edge-agg L2 -> GEMM(W4t)+mean -> graph-sum ----
__global__ __launch_bounds__(128)
void k_fused2(const unsigned char* __restrict__ C, const unsigned char* __restrict__ D,
              const float* __restrict__ b1, const int* __restrict__ offs,
              const int* __restrict__ cnt, const unsigned short* __restrict__ ssrc,
              const unsigned short* __restrict__ W4t, const float* __restrict__ bias,
              const int* __restrict__ nb, float* __restrict__ gsum)
{
  __shared__ unsigned short As[QB*ASS];  // gather result tile, bf16 (2304 B)
  __shared__ float TsEs[QB*65];          // union: Es (phase A) / Ts (epilogue), 4160 B
  unsigned short* Es = reinterpret_cast<unsigned short*>(TsEs);  // 2048 u16 = 4096 B
  float* Ts = TsEs;
  int tid = threadIdx.x;
  int m0 = blockIdx.x*QB;

  int beg0 = offs[m0];
  int end0 = offs[m0 + QB];
  int nwin = end0 - beg0;
  for (int i = tid; i < nwin && i < ECAP; i += 128)
    Es[i] = ssrc[beg0 + i];
  __syncthreads();

  // ---- phase A: edge aggregation, 16 nodes x 8 lanes x 8 ch ----
  {
    int vloc = tid >> 3;
    int v = m0 + vloc;
    int c = tid & 7;                  // channels 8c .. 8c+7
    float s[8];
    #pragma unroll
    for (int q = 0; q < 8; ++q) s[q] = 0.f;
    int beg = offs[v], n = cnt[v];
    if (n > 0){
      int rel = beg - beg0;
      uint2 au = *reinterpret_cast<const uint2*>(&C[(size_t)v*GD + 8*c]);
      float ax[8];
      #pragma unroll
      for (int wq = 0; wq < 2; ++wq){
        unsigned u = (&au.x)[wq];
        f32x2 p0 = fp8x2_to_f32((unsigned short)(u & 0xFFFFu));
        f32x2 p1 = fp8x2_to_f32((unsigned short)(u >> 16));
        float4 bb = *reinterpret_cast<const float4*>(&b1[8*c + 4*wq]);
        ax[wq*4+0] = p0.x + bb.x; ax[wq*4+1] = p0.y + bb.y;
        ax[wq*4+2] = p1.x + bb.z; ax[wq*4+3] = p1.y + bb.w;
      }
      bool fits = (rel + n) <= ECAP;
      if (fits){
        for (int i = 0; i < n; i += 4){
          int ids[4];
          #pragma unroll
          for (int j = 0; j < 4; ++j){
            int t2 = i + j; t2 = (t2 < n) ? t2 : (n - 1);
            ids[j] = (int)Es[rel + t2];
          }
          uint2 du[4];
          #pragma unroll
          for (int j = 0; j < 4; ++j)
            du[j] = *reinterpret_cast<const uint2*>(&D[(size_t)ids[j]*GD + 8*c]);
          #pragma unroll
          for (int j = 0; j < 4; ++j){
            float live = (i + j < n) ? 1.f : 0.f;
            #pragma unroll
            for (int wq = 0; wq < 2; ++wq)
              acc_u32((&du[j].x)[wq], ax + wq*4, s + wq*4, live);
          }
        }
      } else {
        for (int i = 0; i < n; i += 4){
          int ids[4];
          #pragma unroll
          for (int j = 0; j < 4; ++j){
            int t2 = i + j; t2 = (t2 < n) ? t2 : (n - 1);
            ids[j] = (int)ssrc[beg + t2];
          }
          uint2 du[4];
          #pragma unroll
          for (int j = 0; j < 4; ++j)
            du[j] = *reinterpret_cast<const uint2*>(&D[(size_t)ids[j]*GD + 8*c]);
          #pragma unroll
          for (int j = 0; j < 4; ++j){
            float live = (i + j < n) ? 1.f : 0.f;
            #pragma unroll
            for (int wq = 0; wq < 2; ++wq)
              acc_u32((&du[j].x)[wq], ax + wq*4, s + wq*4, live);
          }
        }
      }
    }
    uint4 o;
    o.x = (unsigned)pk2bf(s[0], s[1]); o.y = (unsigned)pk2bf(s[2], s[3]);
    o.z = (unsigned)pk2bf(s[4], s[5]); o.w = (unsigned)pk2bf(s[6], s[7]);
    *reinterpret_cast<uint4*>(&As[vloc*ASS + 8*c]) = o;
  }
  __syncthreads();

  // ---- GEMM: As @ W4t, mean + bias.  2 waves: 16 rows, cols 32x2 ----
  int w = tid >> 6, lane = tid & 63, l15 = tid & 15, quad = lane >> 4;
  int cb = w * 32;
  f32x4 acc[2];
  #pragma unroll
  for (int t = 0; t < 2; ++t) acc[t] = (f32x4){0.f,0.f,0.f,0.f};
  #pragma unroll
  for (int k0 = 0; k0 < 64; k0 += 32){
    short8v ah = *reinterpret_cast<short8v*>(&As[l15*ASS + k0 + quad*8]);
    #pragma unroll
    for (int t = 0; t < 2; ++t){
      short8v bh = *reinterpret_cast<const short8v*>(&W4t[(cb + t*16 + l15)*GD + k0 + quad*8]);
      acc[t] = __builtin_amdgcn_mfma_f32_16x16x32_bf16(ah, bh, acc[t], 0, 0, 0);
    }
  }
  __syncthreads();                      // all Es reads done before Ts writes
  #pragma unroll
  for (int r = 0; r < 4; ++r){
    int ml = quad*4 + r;                // 0..15
    int m = m0 + ml;
    float fcnt = (float)cnt[m];
    float inv = 1.f / fmaxf(fcnt, 1.f);
    #pragma unroll
    for (int t = 0; t < 2; ++t){
      int n = cb + t*16 + l15;
      Ts[ml*65 + n] = (acc[t][r] + fcnt * bias[n]) * inv;
    }
  }
  __syncthreads();
  int col = tid & 63, rg = tid >> 6;    // rg 0..1, 8 rows each
  float a = 0.f; int cur = -1;
  for (int rr = rg*8; rr < rg*8 + 8; ++rr){
    int m = m0 + rr;
    int g = nb[m];
    if (g != cur){ if (cur >= 0) atomicAdd(&gsum[cur*GD + col], a); cur = g; a = 0.f; }
    a += Ts[rr*65 + col];
  }
  if (cur >= 0) atomicAdd(&gsum[cur*GD + col], a);
}

// ---------------- actor head: one block per batch row (divide fused here) -----
__global__ __launch_bounds__(256)
void k_head(const float* __restrict__ state, const float* __restrict__ gsum,
            const int* __restrict__ nb,
            const float* __restrict__ fc1w, const float* __restrict__ fc1b,
            const float* __restrict__ fc2w, const float* __restrict__ fc2b,
            const float* __restrict__ mw, const float* __restrict__ mb,
            const float* __restrict__ lw, const float* __restrict__ lb,
            float* __restrict__ out)
{
  int b = blockIdx.x, t = threadIdx.x;
  __shared__ float z[SD + GD];
  __shared__ float h1[HID];
  __shared__ float h2[HID];
  __shared__ float part[16][17];
  __shared__ int bounds[2];
  if (t < 2){
    int target = b + t;
    int lo = 0, hi = NN;
    while (lo < hi){ int mid = (lo + hi) >> 1; if (nb[mid] < target) lo = mid + 1; else hi = mid; }
    bounds[t] = lo;
  }
  if (t < SD) z[t] = state[b*SD + t];
  __syncthreads();
  if (t >= SD && t < SD + GD){
    float n = (float)(bounds[1] - bounds[0]);
    z[t] = gsum[b*GD + (t - SD)] / fmaxf(n, 1.f);
  }
  __syncthreads();
  float a0 = 0.f, a1 = 0.f;
  #pragma unroll 4
  for (int k = 0; k < SD + GD; k += 2){
    a0 = fmaf(z[k],   fc1w[k*HID + t],     a0);
    a1 = fmaf(z[k+1], fc1w[(k+1)*HID + t], a1);
  }
  h1[t] = fmaxf(a0 + a1 + fc1b[t], 0.f);
  __syncthreads();
  float t0 = 0.f, t1 = 0.f, t2 = 0.f, t3 = 0.f;
  #pragma unroll 4
  for (int k = 0; k < HID; k += 4){
    t0 = fmaf(h1[k],   fc2w[k*HID + t],     t0);
    t1 = fmaf(h1[k+1], fc2w[(k+1)*HID + t], t1);
    t2 = fmaf(h1[k+2], fc2w[(k+2)*HID + t], t2);
    t3 = fmaf(h1[k+3], fc2w[(k+3)*HID + t], t3);
  }
  h2[t] = fmaxf((t0 + t1) + (t2 + t3) + fc2b[t], 0.f);
  __syncthreads();
  { int j = t & 15, p = t >> 4;
    const float* wv = (j < 8) ? mw : lw;
    int colj = j & 7;
    float a = 0.f;
    #pragma unroll
    for (int k = 0; k < 16; ++k)
      a = fmaf(h2[p*16 + k], wv[(p*16 + k)*AD + colj], a);
    part[p][j] = a;
  }
  __syncthreads();
  if (t < 16){
    float sum = (t < 8) ? mb[t] : lb[t - 8];
    #pragma unroll
    for (int p2 = 0; p2 < 16; ++p2) sum += part[p2][t];
    if (t < 8) out[b*AD + t] = sum;
    else       out[NB*AD + b*AD + (t - 8)] = fminf(fmaxf(sum, -20.f), 2.f);
  }
}

extern "C" void kernel_launch(void* const* d_in, const int* in_sizes, int n_in,
                              void* d_out, int out_size, void* d_ws, size_t ws_size,
                              hipStream_t stream)
{
  const float* state = (const float*)d_in[0];
  const float* x     = (const float*)d_in[1];
  const int*   eidx  = (const int*)  d_in[2];
  const int*   nb    = (const int*)  d_in[3];
  const float* g1w1  = (const float*)d_in[4];
  const float* g1b1  = (const float*)d_in[5];
  const float* g1w2  = (const float*)d_in[6];
  const float* g1b2  = (const float*)d_in[7];
  const float* g2w1  = (const float*)d_in[8];
  const float* g2b1  = (const float*)d_in[9];
  const float* g2w2  = (const float*)d_in[10];
  const float* g2b2  = (const float*)d_in[11];
  const float* fc1w  = (const float*)d_in[12];
  const float* fc1b  = (const float*)d_in[13];
  const float* fc2w  = (const float*)d_in[14];
  const float* fc2b  = (const float*)d_in[15];
  const float* mw    = (const float*)d_in[16];
  const float* mb    = (const float*)d_in[17];
  const float* lw    = (const float*)d_in[18];
  const float* lb    = (const float*)d_in[19];

  const int* e_src = eidx;        // edge_index[0]
  const int* e_dst = eidx + NE;   // edge_index[1]

  char* p = (char*)d_ws;
  auto alloc = [&](size_t bytes){ char* r = p; p += align256(bytes); return r; };
  int*   cnt8   = (int*)  alloc((size_t)NP*CPAD*4); // partial hists; contiguous w/ gsum
  float* gsum   = (float*)alloc((size_t)NB*GD*4);
  int*   cnt    = (int*)  alloc((size_t)CPAD*4);    // totals
  int*   offs   = (int*)  alloc((size_t)CPAD*4);
  int*   offs8  = (int*)  alloc((size_t)NP*CPAD*4); // per-partition bases
  int*   tot    = (int*)  alloc((size_t)CPAD*4);
  int*   npfx   = (int*)  alloc((size_t)CPAD*4);
  int*   bsum   = (int*)  alloc((size_t)SB*4);
  unsigned short* rank = (unsigned short*)alloc((size_t)NE*2);
  unsigned short* ssrc = (unsigned short*)alloc((size_t)NE*2);
  unsigned char*  fA8 = (unsigned char*) alloc((size_t)NN2*GH);    // fp8 [NN2,128]
  unsigned char*  fB8 = (unsigned char*) alloc((size_t)NN2*GH);    // fp8 [NN2,128]
  unsigned char*  fC8 = (unsigned char*) alloc((size_t)NN*GD);     // fp8 [NN,64]
  unsigned char*  fD8 = (unsigned char*) alloc((size_t)NN*GD);     // fp8 [NN,64]
  unsigned short* W2t = (unsigned short*)alloc((size_t)GH*GH*2);   // bf16 [128][128] (n,k)
  unsigned short* W3t = (unsigned short*)alloc((size_t)GH*GH*2);   // bf16 [128][128] (n,k)
  unsigned short* W4t = (unsigned short*)alloc((size_t)GD*GD*2);   // bf16 [64][64]  (n,k)

  hipMemsetAsync(cnt8, 0, (size_t)NP*CPAD*4 + (size_t)NB*GD*4, stream);

  dim3 b256(256), b128(128), b1024(1024);
  k_pre<<<dim3(EB + MB*2 + NCV), b256, 0, stream>>>(e_dst, cnt8, rank, x, g1w1, fA8, fB8,
                                                    g1w2, g2w1, g2w2, W2t, W3t, W4t);
  k_scanA<<<dim3(SB), b1024, 0, stream>>>(cnt8, tot, npfx, bsum);
  k_scanB<<<dim3(SB), b1024, 0, stream>>>(cnt8, tot, npfx, bsum, cnt, offs, offs8);
  k_place <<<dim3(EB), b256, 0, stream>>>(e_src, e_dst, offs8, rank, ssrc);

  k_fused1<<<dim3(NT), b128, 0, stream>>>(fA8, fB8, g1b1, offs, cnt, ssrc,
                                          W2t, W3t, g1b2, fC8, fD8);
  k_fused2<<<dim3(NT), b128, 0, stream>>>(fC8, fD8, g2b1, offs, cnt, ssrc,
                                          W4t, g2b2, nb, gsum);
  k_head<<<dim3(NB), b256, 0, stream>>>(state, gsum, nb, fc1w, fc1b, fc2w, fc2b,
                                        mw, mb, lw, lb, (float*)d_out);
}